// Round 5
// baseline (392.388 us; speedup 1.0000x reference)
//
#include <hip/hip_runtime.h>

#define NP 256      // P
#define NDD 128     // DD
#define NN 1024     // N
#define NE 250000   // E
#define SB 62       // ceil(NE/4096) blocks per layer for hist/scatter

// ---------------------------------------------------------------------------
// K1: refine rows [target; form(1024); role(1024)] : z = W2 @ prelu(W1 @ x + b1) + b2
// 4 rows/block, 256 threads. Block 0 additionally computes qk/s0 (depends only
// on its own zt row). Blocks 1,2 zero count/cursor (used by hist/scatter later).
// ---------------------------------------------------------------------------
__global__ __launch_bounds__(256) void refine_qk_kernel(
    const float* __restrict__ tgt, const float* __restrict__ formf, const float* __restrict__ rolef,
    const float* __restrict__ Wr1, const float* __restrict__ br1, const float* __restrict__ ar1,
    const float* __restrict__ Wr2, const float* __restrict__ br2,
    const float* __restrict__ Wq, const float* __restrict__ bq,
    const float* __restrict__ Wk, const float* __restrict__ bk,
    float* __restrict__ zt, float* __restrict__ zf, float* __restrict__ zr,
    float* __restrict__ qk, float* __restrict__ s0,
    int* __restrict__ count, int* __restrict__ cursor0)
{
  __shared__ float X[4][NP];
  __shared__ float H[4][NP];
  __shared__ float Zs[NP];
  __shared__ float Q[NDD];
  __shared__ float red[NDD];
  const int t = threadIdx.x;
  const int base = blockIdx.x * 4;

  // zero the count/cursor arrays (consumed by hist/scatter after this kernel)
  if (blockIdx.x == 1){
    #pragma unroll
    for (int i = 0; i < 8; i++) count[t + i*256] = 0;
  } else if (blockIdx.x == 2){
    #pragma unroll
    for (int i = 0; i < 8; i++) cursor0[t + i*256] = 0;
  }

  #pragma unroll
  for (int r = 0; r < 4; r++){
    int row = base + r;
    if (row < 2*NN + 1){
      const float* xp;
      if (row == 0)        xp = tgt;
      else if (row <= NN)  xp = formf + (size_t)(row-1)*NP;
      else                 xp = rolef + (size_t)(row-NN-1)*NP;
      X[r][t] = xp[t];
    } else {
      X[r][t] = 0.f;
    }
  }
  __syncthreads();
  const float a1 = ar1[0];
  float acc[4];
  #pragma unroll
  for (int r = 0; r < 4; r++) acc[r] = 0.f;
  const float4* w1p = reinterpret_cast<const float4*>(Wr1) + t*(NP/4);
  for (int k4 = 0; k4 < NP/4; k4++){
    float4 w = w1p[k4];
    #pragma unroll
    for (int r = 0; r < 4; r++){
      float4 xv = *reinterpret_cast<const float4*>(&X[r][k4*4]);
      acc[r] = fmaf(w.x, xv.x, acc[r]);
      acc[r] = fmaf(w.y, xv.y, acc[r]);
      acc[r] = fmaf(w.z, xv.z, acc[r]);
      acc[r] = fmaf(w.w, xv.w, acc[r]);
    }
  }
  const float b1 = br1[t];
  #pragma unroll
  for (int r = 0; r < 4; r++){
    float h = acc[r] + b1;
    H[r][t] = h >= 0.f ? h : a1*h;
  }
  __syncthreads();
  #pragma unroll
  for (int r = 0; r < 4; r++) acc[r] = 0.f;
  const float4* w2p = reinterpret_cast<const float4*>(Wr2) + t*(NP/4);
  for (int k4 = 0; k4 < NP/4; k4++){
    float4 w = w2p[k4];
    #pragma unroll
    for (int r = 0; r < 4; r++){
      float4 hv = *reinterpret_cast<const float4*>(&H[r][k4*4]);
      acc[r] = fmaf(w.x, hv.x, acc[r]);
      acc[r] = fmaf(w.y, hv.y, acc[r]);
      acc[r] = fmaf(w.z, hv.z, acc[r]);
      acc[r] = fmaf(w.w, hv.w, acc[r]);
    }
  }
  const float b2 = br2[t];
  #pragma unroll
  for (int r = 0; r < 4; r++){
    int row = base + r;
    if (row < 2*NN + 1){
      float v = acc[r] + b2;
      float* op;
      if (row == 0){ op = zt; Zs[t] = v; }
      else if (row <= NN)  op = zf + (size_t)(row-1)*NP;
      else                 op = zr + (size_t)(row-NN-1)*NP;
      op[t] = v;
    }
  }

  // block 0: qk = (Wk^T @ (Wq@zt+bq))/sqrt(DD); s0 = (bk.(Wq@zt+bq))/sqrt(DD)
  if (blockIdx.x == 0){
    __syncthreads();               // Zs complete
    if (t < NDD){
      float a = 0.f;
      const float4* wq = reinterpret_cast<const float4*>(Wq) + t*(NP/4);
      for (int k4 = 0; k4 < NP/4; k4++){
        float4 w = wq[k4];
        float4 zv = *reinterpret_cast<const float4*>(&Zs[k4*4]);
        a = fmaf(w.x, zv.x, fmaf(w.y, zv.y, fmaf(w.z, zv.z, fmaf(w.w, zv.w, a))));
      }
      float qv = a + bq[t];
      Q[t] = qv;
      red[t] = bk[t] * qv;
    }
    __syncthreads();
    const float rs = 0.08838834764831845f;  // 1/sqrt(128)
    if (t < NDD){
      float a2 = 0.f;
      for (int j = 0; j < NDD; j++) a2 = fmaf(Wk[j*NDD + t], Q[j], a2);
      qk[t] = a2 * rs;
    }
    for (int o = 64; o; o >>= 1){
      if (t < o) red[t] += red[t+o];
      __syncthreads();
    }
    if (t == 0) s0[0] = red[0] * rs;
  }
}

// ---------------------------------------------------------------------------
// Segment id: fast path (sorted int neighbors with neigh[s]==s => pos=s),
// fallback to binary search.
// ---------------------------------------------------------------------------
__device__ __forceinline__ int seg_of(const int* NB, int s){
  if ((unsigned)s < NN && NB[s] == s) return s;
  int lo = 0, hi = NN;
  while (lo < hi){ int mid = (lo+hi)>>1; if (NB[mid] < s) lo = mid+1; else hi = mid; }
  return lo < NN ? lo : NN-1;
}

// ---------------------------------------------------------------------------
// K2: histogram by segment, two-level: LDS histogram per block (4096 edges),
// then one global atomicAdd per nonzero bin. Both layers in one launch.
// ---------------------------------------------------------------------------
__global__ __launch_bounds__(1024) void hist_kernel(
    const int* __restrict__ neighF, const int* __restrict__ srcF,
    const int* __restrict__ neighR, const int* __restrict__ srcR,
    int* __restrict__ count)
{
  __shared__ int NB[NN];
  __shared__ int lh[NN];
  int bi = blockIdx.x;
  int role = bi >= SB ? 1 : 0;
  int blk = bi - role*SB;
  const int* neigh = role ? neighR : neighF;
  const int* src   = role ? srcR   : srcF;
  int* cnt = count + role*NN;
  int t = threadIdx.x;
  NB[t] = neigh[t];
  lh[t] = 0;
  __syncthreads();
  #pragma unroll
  for (int i = 0; i < 4; i++){
    int e = blk*4096 + i*1024 + t;
    if (e < NE){
      int s = src[e];
      int pos = seg_of(NB, s);
      if (NB[pos] == s) atomicAdd(&lh[pos], 1);
    }
  }
  __syncthreads();
  int c = lh[t];
  if (c > 0) atomicAdd(&cnt[t], c);
}

// ---------------------------------------------------------------------------
// K3: scatter edges into segment-sorted order. Absorbs the scan: every block
// redundantly computes the exclusive prefix sum of count in LDS; a zero-based
// global cursor gives each block a contiguous slot range per segment.
// Block 0 of each layer publishes the offsets array for seg_kernel.
// ---------------------------------------------------------------------------
__global__ __launch_bounds__(1024) void scatter_kernel(
    const int* __restrict__ neighF, const int* __restrict__ srcF,
    const int* __restrict__ dstF, const float* __restrict__ yF,
    const int* __restrict__ neighR, const int* __restrict__ srcR,
    const int* __restrict__ dstR, const float* __restrict__ yR,
    const int* __restrict__ count, int* __restrict__ cursor0,
    int* __restrict__ offsets, int2* __restrict__ edges)
{
  __shared__ int NB[NN];
  __shared__ int lcur[NN];
  __shared__ int sscan[NN];
  __shared__ int obase[NN];
  __shared__ int lbase[NN];
  int bi = blockIdx.x;
  int role = bi >= SB ? 1 : 0;
  int blk = bi - role*SB;
  const int* neigh = role ? neighR : neighF;
  const int* src   = role ? srcR   : srcF;
  const int* dst   = role ? dstR   : dstF;
  const float* yb  = role ? yR     : yF;
  int* cur0 = cursor0 + role*NN;
  int2* ed  = edges   + (size_t)role*NE;
  int t = threadIdx.x;
  NB[t] = neigh[t];
  lcur[t] = 0;
  int c0 = count[role*NN + t];
  sscan[t] = c0;
  __syncthreads();
  // exclusive scan of counts
  for (int o = 1; o < NN; o <<= 1){
    int v = (t >= o) ? sscan[t-o] : 0;
    __syncthreads();
    sscan[t] += v;
    __syncthreads();
  }
  obase[t] = sscan[t] - c0;
  if (blk == 0) offsets[role*NN + t] = sscan[t] - c0;
  __syncthreads();

  int segr[4], locr[4]; int2 edr[4];
  #pragma unroll
  for (int i = 0; i < 4; i++){
    int e = blk*4096 + i*1024 + t;
    segr[i] = -1;
    if (e < NE){
      int s = src[e];
      int pos = seg_of(NB, s);
      if (NB[pos] == s){
        segr[i] = pos;
        edr[i]  = make_int2(dst[e], __float_as_int(yb[e]));
        locr[i] = atomicAdd(&lcur[pos], 1);
      }
    }
  }
  __syncthreads();
  int c = lcur[t];
  if (c > 0) lbase[t] = obase[t] + atomicAdd(&cur0[t], c);
  __syncthreads();
  #pragma unroll
  for (int i = 0; i < 4; i++){
    if (segr[i] >= 0){
      ed[(size_t)(lbase[segr[i]] + locr[i])] = edr[i];
    }
  }
}

// ---------------------------------------------------------------------------
// K4: per-(layer,segment) softmax-weighted accumulation.
// 4 waves/block; each 32-lane half-wave handles one edge with float4 lanes.
// No max-subtraction: logits are O(1e-2), exp safe; num/den invariant.
// ---------------------------------------------------------------------------
__global__ __launch_bounds__(256) void seg_kernel(
    const float* __restrict__ drug,
    const int2* __restrict__ edges,
    const int* __restrict__ offsets, const int* __restrict__ count,
    const float* __restrict__ qk, const float* __restrict__ s0p,
    float* __restrict__ g, float* __restrict__ den, float* __restrict__ cfac)
{
  int b = blockIdx.x;                 // l*1024 + n
  int tid = threadIdx.x;
  int w = tid >> 6, lane = tid & 63, l32 = lane & 31, half = lane >> 5;
  int off = offsets[b], cnt = count[b];
  int l = b >> 10;
  const int2* eb = edges + (size_t)l*NE;
  float4 q = reinterpret_cast<const float4*>(qk)[l32];
  float s0 = s0p[0];
  int chunk = (cnt + 3) >> 2;
  int start = w*chunk;
  int end = min(start + chunk, cnt);
  float dn = 0.f, cc = 0.f;
  float4 ga = make_float4(0.f,0.f,0.f,0.f);
  for (int i = start; i < end; i += 8){
    int dstp[4]; float yp[4]; bool vp[4];
    #pragma unroll
    for (int p2 = 0; p2 < 4; p2++){
      int idx = i + 2*p2 + half;
      bool v = idx < end;
      int2 e = eb[off + (v ? idx : start)];
      dstp[p2] = e.x; yp[p2] = __int_as_float(e.y); vp[p2] = v;
    }
    float4 dv[4];
    #pragma unroll
    for (int p2 = 0; p2 < 4; p2++){
      dv[p2] = reinterpret_cast<const float4*>(drug + (size_t)dstp[p2]*NDD)[l32];
    }
    #pragma unroll
    for (int p2 = 0; p2 < 4; p2++){
      float4 d = dv[p2];
      float s = fmaf(d.x, q.x, fmaf(d.y, q.y, fmaf(d.z, q.z, d.w*q.w)));
      s += __shfl_xor(s, 16, 64);
      s += __shfl_xor(s,  8, 64);
      s += __shfl_xor(s,  4, 64);
      s += __shfl_xor(s,  2, 64);
      s += __shfl_xor(s,  1, 64);
      float ex = vp[p2] ? __expf(s + s0) : 0.f;
      float wv = ex * (yp[p2] - 6.0f);
      dn += ex; cc += wv;
      ga.x = fmaf(wv, d.x, ga.x);
      ga.y = fmaf(wv, d.y, ga.y);
      ga.z = fmaf(wv, d.z, ga.z);
      ga.w = fmaf(wv, d.w, ga.w);
    }
  }
  __shared__ float4 sG[8][32];
  __shared__ float sD[8], sC[8];
  int slot = w*2 + half;
  sG[slot][l32] = ga;
  if (l32 == 0){ sD[slot] = dn; sC[slot] = cc; }
  __syncthreads();
  if (tid < NDD){
    int a = tid >> 2, c = tid & 3;
    float v = 0.f;
    #pragma unroll
    for (int k = 0; k < 8; k++)
      v += reinterpret_cast<const float*>(&sG[k][a])[c];
    g[(size_t)b*NDD + tid] = v;
    if (tid == 0){
      float ds = 0.f, cs = 0.f;
      #pragma unroll
      for (int k = 0; k < 8; k++){ ds += sD[k]; cs += sC[k]; }
      den[b] = ds; cfac[b] = cs;
    }
  }
}

// ---------------------------------------------------------------------------
// K5: fused attn (blocks 0..255) + msgs (blocks 256..511), 256 threads each.
// attn: a_i = Wa3 @ lrelu(Wa2 @ lrelu(Wa1 @ [zt,zn,le] + ba1) + ba2) + ba3
// msgs: msgs[row] = (Wv @ g[row] + bv*c[row]) / den[row]
// ---------------------------------------------------------------------------
__global__ __launch_bounds__(256) void attn_msgs_kernel(
    const float* __restrict__ zt, const float* __restrict__ zf, const float* __restrict__ zr,
    const float* __restrict__ lemb,
    const float* __restrict__ Wa1, const float* __restrict__ ba1,
    const float* __restrict__ Wa2, const float* __restrict__ ba2,
    const float* __restrict__ Wa3, const float* __restrict__ ba3,
    const float* __restrict__ g, const float* __restrict__ den, const float* __restrict__ cfac,
    const float* __restrict__ Wv, const float* __restrict__ bv,
    float* __restrict__ attn, float* __restrict__ msgsf, float* __restrict__ outm)
{
  int t = threadIdx.x;
  int tt = t & 127, grp = t >> 7;
  if (blockIdx.x < 256){
    // ---------------- attn ----------------
    __shared__ float X[8][528];
    __shared__ float H1[8][NDD];
    int base = blockIdx.x*8;
    for (int r = 0; r < 8; r++){
      int i = base + r;
      int layer = i >> 10, nn = i & (NN-1);
      const float* zn = (layer == 0) ? (zf + (size_t)nn*NP) : (zr + (size_t)nn*NP);
      for (int idx = t; idx < 528; idx += 256){
        float v;
        if (idx < NP)        v = zt[idx];
        else if (idx < 2*NP) v = zn[idx - NP];
        else                 v = lemb[layer*16 + (idx - 2*NP)];
        X[r][idx] = v;
      }
    }
    __syncthreads();
    float acc[4];
    #pragma unroll
    for (int r = 0; r < 4; r++) acc[r] = 0.f;
    const float4* w1 = reinterpret_cast<const float4*>(Wa1) + tt*(528/4);
    for (int k4 = 0; k4 < 132; k4++){
      float4 w = w1[k4];
      #pragma unroll
      for (int r = 0; r < 4; r++){
        float4 xv = *reinterpret_cast<const float4*>(&X[grp*4 + r][k4*4]);
        acc[r] = fmaf(w.x, xv.x, acc[r]);
        acc[r] = fmaf(w.y, xv.y, acc[r]);
        acc[r] = fmaf(w.z, xv.z, acc[r]);
        acc[r] = fmaf(w.w, xv.w, acc[r]);
      }
    }
    float b1 = ba1[tt];
    #pragma unroll
    for (int r = 0; r < 4; r++){
      float h = acc[r] + b1;
      H1[grp*4 + r][tt] = h >= 0.f ? h : 0.2f*h;
    }
    __syncthreads();
    if (tt < 64){
      float acc2[4];
      #pragma unroll
      for (int r = 0; r < 4; r++) acc2[r] = 0.f;
      const float4* w2 = reinterpret_cast<const float4*>(Wa2) + tt*(NDD/4);
      for (int k4 = 0; k4 < NDD/4; k4++){
        float4 w = w2[k4];
        #pragma unroll
        for (int r = 0; r < 4; r++){
          float4 hv = *reinterpret_cast<const float4*>(&H1[grp*4 + r][k4*4]);
          acc2[r] = fmaf(w.x, hv.x, acc2[r]);
          acc2[r] = fmaf(w.y, hv.y, acc2[r]);
          acc2[r] = fmaf(w.z, hv.z, acc2[r]);
          acc2[r] = fmaf(w.w, hv.w, acc2[r]);
        }
      }
      float b2 = ba2[tt];
      float w3 = Wa3[tt];
      float b3 = ba3[0];
      #pragma unroll
      for (int r = 0; r < 4; r++){
        float h = acc2[r] + b2;
        h = h >= 0.f ? h : 0.2f*h;
        float p = w3 * h;
        #pragma unroll
        for (int o = 32; o; o >>= 1) p += __shfl_xor(p, o, 64);
        if (tt == 0) attn[base + grp*4 + r] = p + b3;
      }
    }
  } else {
    // ---------------- msgs ----------------
    __shared__ float G[8][NDD];
    int base = (blockIdx.x - 256)*8;
    #pragma unroll
    for (int r = 0; r < 4; r++) G[grp*4 + r][tt] = g[(size_t)(base + grp*4 + r)*NDD + tt];
    __syncthreads();
    float acc[4];
    #pragma unroll
    for (int r = 0; r < 4; r++) acc[r] = 0.f;
    const float4* wv4 = reinterpret_cast<const float4*>(Wv) + tt*(NDD/4);
    for (int k4 = 0; k4 < NDD/4; k4++){
      float4 w = wv4[k4];
      #pragma unroll
      for (int r = 0; r < 4; r++){
        float4 gv = *reinterpret_cast<const float4*>(&G[grp*4 + r][k4*4]);
        acc[r] = fmaf(w.x, gv.x, acc[r]);
        acc[r] = fmaf(w.y, gv.y, acc[r]);
        acc[r] = fmaf(w.z, gv.z, acc[r]);
        acc[r] = fmaf(w.w, gv.w, acc[r]);
      }
    }
    float bvj = bv[tt];
    #pragma unroll
    for (int r = 0; r < 4; r++){
      int row = base + grp*4 + r;
      float dn = den[row];
      float v = 0.f;
      if (dn > 0.f) v = (acc[r] + bvj*cfac[row]) / fmaxf(dn, 1e-30f);
      msgsf[(size_t)row*NDD + tt] = v;
      outm [(size_t)row*NDD + tt] = v;
    }
  }
}

// ---------------------------------------------------------------------------
// K6: fused vprior + final. One 1024-thread block.
// vprior: softmax over 2048 logits, v = sum w_i*msgs_i (to LDS)
// final: integ = Wi2 @ prelu(Wi1 @ v + bi1) + bi2 ; x = zt+integ ; layernorm
// ---------------------------------------------------------------------------
__global__ __launch_bounds__(1024) void vprior_final_kernel(
    const float* __restrict__ attn, const float* __restrict__ msgsf,
    const float* __restrict__ zt,
    const float* __restrict__ Wi1, const float* __restrict__ bi1, const float* __restrict__ ai,
    const float* __restrict__ Wi2, const float* __restrict__ bi2,
    const float* __restrict__ ln_g, const float* __restrict__ ln_b,
    float* __restrict__ zout)
{
  __shared__ float A[2*NN];
  __shared__ float red[1024];
  __shared__ float Pp[8][NDD];
  __shared__ float V[NDD];
  __shared__ float T1[NP];
  __shared__ float red2[NP];
  int t = threadIdx.x;
  A[t] = attn[t]; A[t+1024] = attn[t+1024];
  __syncthreads();
  float mx = fmaxf(A[t], A[t+1024]);
  red[t] = mx; __syncthreads();
  for (int o = 512; o; o >>= 1){ if (t < o) red[t] = fmaxf(red[t], red[t+o]); __syncthreads(); }
  float M = red[0]; __syncthreads();
  float sm = __expf(A[t] - M) + __expf(A[t+1024] - M);
  red[t] = sm; __syncthreads();
  for (int o = 512; o; o >>= 1){ if (t < o) red[t] += red[t+o]; __syncthreads(); }
  float inv = 1.f / red[0]; __syncthreads();
  A[t]      = __expf(A[t]      - M) * inv;
  A[t+1024] = __expf(A[t+1024] - M) * inv;
  __syncthreads();
  int j = t & 127, grp = t >> 7;          // 8 groups x 128 dims
  float acc = 0.f;
  int i0 = grp * 256;
  for (int i = i0; i < i0 + 256; i++) acc = fmaf(A[i], msgsf[(size_t)i*NDD + j], acc);
  Pp[grp][j] = acc;
  __syncthreads();
  if (t < NDD){
    float v = 0.f;
    #pragma unroll
    for (int gg = 0; gg < 8; gg++) v += Pp[gg][t];
    V[t] = v;
  }
  __syncthreads();
  // ---- final (threads 0..255 active; syncs are block-wide) ----
  float x = 0.f;
  if (t < NP){
    float a1 = 0.f;
    const float4* w1 = reinterpret_cast<const float4*>(Wi1) + t*(NDD/4);
    for (int k4 = 0; k4 < NDD/4; k4++){
      float4 w = w1[k4];
      float4 vv = *reinterpret_cast<const float4*>(&V[k4*4]);
      a1 = fmaf(w.x, vv.x, fmaf(w.y, vv.y, fmaf(w.z, vv.z, fmaf(w.w, vv.w, a1))));
    }
    float h = a1 + bi1[t];
    float a = ai[0];
    T1[t] = h >= 0.f ? h : a*h;
  }
  __syncthreads();
  if (t < NP){
    float a2 = 0.f;
    const float4* w2 = reinterpret_cast<const float4*>(Wi2) + t*(NP/4);
    for (int k4 = 0; k4 < NP/4; k4++){
      float4 w = w2[k4];
      float4 hv = *reinterpret_cast<const float4*>(&T1[k4*4]);
      a2 = fmaf(w.x, hv.x, fmaf(w.y, hv.y, fmaf(w.z, hv.z, fmaf(w.w, hv.w, a2))));
    }
    x = zt[t] + a2 + bi2[t];
    red2[t] = x;
  }
  __syncthreads();
  for (int o = 128; o; o >>= 1){ if (t < o) red2[t] += red2[t+o]; __syncthreads(); }
  float mu = red2[0] * (1.f/256.f); __syncthreads();
  float d = x - mu;
  if (t < NP) red2[t] = d*d;
  __syncthreads();
  for (int o = 128; o; o >>= 1){ if (t < o) red2[t] += red2[t+o]; __syncthreads(); }
  if (t < NP){
    float var = red2[0] * (1.f/256.f);
    float zz = d * rsqrtf(var + 1e-5f) * ln_g[t] + ln_b[t];
    zout[t] = zz;
  }
}

// ---------------------------------------------------------------------------
extern "C" void kernel_launch(void* const* d_in, const int* in_sizes, int n_in,
                              void* d_out, int out_size, void* d_ws, size_t ws_size,
                              hipStream_t stream)
{
  const float* tgt    = (const float*)d_in[0];
  const float* formf  = (const float*)d_in[1];
  const float* rolef  = (const float*)d_in[2];
  const int* fneigh   = (const int*)d_in[3];
  const int* fsrc     = (const int*)d_in[4];
  const int* fdst     = (const int*)d_in[5];
  const float* fy     = (const float*)d_in[6];
  const int* rneigh   = (const int*)d_in[7];
  const int* rsrc     = (const int*)d_in[8];
  const int* rdst     = (const int*)d_in[9];
  const float* ry     = (const float*)d_in[10];
  const float* drug   = (const float*)d_in[11];
  const float* Wr1 = (const float*)d_in[12];
  const float* br1 = (const float*)d_in[13];
  const float* ar1 = (const float*)d_in[14];
  const float* Wr2 = (const float*)d_in[15];
  const float* br2 = (const float*)d_in[16];
  const float* Wq  = (const float*)d_in[17];
  const float* bq  = (const float*)d_in[18];
  const float* Wk  = (const float*)d_in[19];
  const float* bk  = (const float*)d_in[20];
  const float* Wv  = (const float*)d_in[21];
  const float* bv  = (const float*)d_in[22];
  const float* lemb= (const float*)d_in[23];
  const float* Wa1 = (const float*)d_in[24];
  const float* ba1 = (const float*)d_in[25];
  const float* Wa2 = (const float*)d_in[26];
  const float* ba2 = (const float*)d_in[27];
  const float* Wa3 = (const float*)d_in[28];
  const float* ba3 = (const float*)d_in[29];
  const float* Wi1 = (const float*)d_in[30];
  const float* bi1 = (const float*)d_in[31];
  const float* ai  = (const float*)d_in[32];
  const float* Wi2 = (const float*)d_in[33];
  const float* bi2 = (const float*)d_in[34];
  const float* lng = (const float*)d_in[35];
  const float* lnb = (const float*)d_in[36];
  (void)in_sizes; (void)n_in; (void)out_size; (void)ws_size;

  float* ws = (float*)d_ws;
  // ws layout (float offsets)
  float* zt_     = ws + 0;
  float* zf_     = ws + 256;
  float* zr_     = ws + 262400;
  float* qk_     = ws + 524544;
  float* s0_     = ws + 524672;
  float* attn_   = ws + 524800;
  float* den_    = ws + 527104;
  float* cfac_   = ws + 529152;
  float* g_      = ws + 531200;
  float* msgsf_  = ws + 793344;
  int*   count_  = (int*)(ws + 1055488);
  int*   offs_   = (int*)(ws + 1057536);
  int*   cursor_ = (int*)(ws + 1059584);
  int2*  edges_  = (int2*)(ws + 1061632);   // 2*NE int2 = 1M ints

  refine_qk_kernel<<<513, 256, 0, stream>>>(tgt, formf, rolef, Wr1, br1, ar1, Wr2, br2,
                                            Wq, bq, Wk, bk,
                                            zt_, zf_, zr_, qk_, s0_, count_, cursor_);

  hist_kernel<<<2*SB, 1024, 0, stream>>>(fneigh, fsrc, rneigh, rsrc, count_);
  scatter_kernel<<<2*SB, 1024, 0, stream>>>(fneigh, fsrc, fdst, fy,
                                            rneigh, rsrc, rdst, ry,
                                            count_, cursor_, offs_, edges_);

  seg_kernel<<<2*NN, 256, 0, stream>>>(drug, edges_, offs_, count_, qk_, s0_,
                                       g_, den_, cfac_);

  attn_msgs_kernel<<<512, 256, 0, stream>>>(zt_, zf_, zr_, lemb,
                                            Wa1, ba1, Wa2, ba2, Wa3, ba3,
                                            g_, den_, cfac_, Wv, bv,
                                            attn_, msgsf_, (float*)d_out + NP);
  vprior_final_kernel<<<1, 1024, 0, stream>>>(attn_, msgsf_, zt_,
                                              Wi1, bi1, ai, Wi2, bi2,
                                              lng, lnb, (float*)d_out);
}

// Round 6
// 390.832 us; speedup vs baseline: 1.0040x; 1.0040x over previous
//
#include <hip/hip_runtime.h>

#define NP 256      // P
#define NDD 128     // DD
#define NN 1024     // N
#define NE 250000   // E
#define SB 62       // ceil(NE/4096) blocks per layer for hist/scatter
#define RB 129      // ceil(2049/16) refine blocks

// ---------------------------------------------------------------------------
// K1: fused refine (blocks 0..RB-1) + hist (blocks RB..RB+2*SB-1).
// refine: 16 rows/block, 256 threads (thread = output feature).
//   z = W2 @ prelu(W1 @ x + b1) + b2 ; block 0 also computes qk/s0.
// hist: per-block LDS histogram of 4096 edges by segment, one global
//   atomicAdd per nonzero bin. count/cursor pre-zeroed by hipMemsetAsync.
// ---------------------------------------------------------------------------
__global__ __launch_bounds__(256) void refine_qk_hist_kernel(
    const float* __restrict__ tgt, const float* __restrict__ formf, const float* __restrict__ rolef,
    const float* __restrict__ Wr1, const float* __restrict__ br1, const float* __restrict__ ar1,
    const float* __restrict__ Wr2, const float* __restrict__ br2,
    const float* __restrict__ Wq, const float* __restrict__ bq,
    const float* __restrict__ Wk, const float* __restrict__ bk,
    const int* __restrict__ neighF, const int* __restrict__ srcF,
    const int* __restrict__ neighR, const int* __restrict__ srcR,
    float* __restrict__ zt, float* __restrict__ zf, float* __restrict__ zr,
    float* __restrict__ qk, float* __restrict__ s0,
    int* __restrict__ count)
{
  __shared__ float X[16][NP];     // 16 KB (hist overlays NB/lh here)
  __shared__ float H[16][NP];     // 16 KB
  __shared__ float Zs[NP];
  __shared__ float Q[NDD];
  __shared__ float red[NDD];
  const int t = threadIdx.x;

  if (blockIdx.x >= RB){
    // ------------------------- hist path -------------------------
    int bi = blockIdx.x - RB;
    int role = bi >= SB ? 1 : 0;
    int blk = bi - role*SB;
    const int* neigh = role ? neighR : neighF;
    const int* src   = role ? srcR   : srcF;
    int* cnt = count + role*NN;
    int* NB = (int*)&X[0][0];
    int* lh = NB + NN;
    #pragma unroll
    for (int i = 0; i < NN/256; i++){
      NB[t + i*256] = neigh[t + i*256];
      lh[t + i*256] = 0;
    }
    __syncthreads();
    #pragma unroll
    for (int i = 0; i < 16; i++){
      int e = blk*4096 + i*256 + t;
      if (e < NE){
        int s = src[e];
        // fast path: identity neighbors; fallback binary search
        int pos;
        if ((unsigned)s < NN && NB[s] == s) pos = s;
        else {
          int lo = 0, hi = NN;
          while (lo < hi){ int mid = (lo+hi)>>1; if (NB[mid] < s) lo = mid+1; else hi = mid; }
          pos = lo < NN ? lo : NN-1;
        }
        if (NB[pos] == s) atomicAdd(&lh[pos], 1);
      }
    }
    __syncthreads();
    #pragma unroll
    for (int i = 0; i < NN/256; i++){
      int c = lh[t + i*256];
      if (c > 0) atomicAdd(&cnt[t + i*256], c);
    }
    return;
  }

  // ------------------------- refine path -------------------------
  const int base = blockIdx.x * 16;
  #pragma unroll
  for (int r = 0; r < 16; r++){
    int row = base + r;
    if (row < 2*NN + 1){
      const float* xp;
      if (row == 0)        xp = tgt;
      else if (row <= NN)  xp = formf + (size_t)(row-1)*NP;
      else                 xp = rolef + (size_t)(row-NN-1)*NP;
      X[r][t] = xp[t];
    } else {
      X[r][t] = 0.f;
    }
  }
  __syncthreads();
  const float a1 = ar1[0];
  float acc[16];
  #pragma unroll
  for (int r = 0; r < 16; r++) acc[r] = 0.f;
  const float4* w1p = reinterpret_cast<const float4*>(Wr1) + t*(NP/4);
  for (int k4 = 0; k4 < NP/4; k4++){
    float4 w = w1p[k4];
    #pragma unroll
    for (int r = 0; r < 16; r++){
      float4 xv = *reinterpret_cast<const float4*>(&X[r][k4*4]);
      acc[r] = fmaf(w.x, xv.x, acc[r]);
      acc[r] = fmaf(w.y, xv.y, acc[r]);
      acc[r] = fmaf(w.z, xv.z, acc[r]);
      acc[r] = fmaf(w.w, xv.w, acc[r]);
    }
  }
  const float b1 = br1[t];
  #pragma unroll
  for (int r = 0; r < 16; r++){
    float h = acc[r] + b1;
    H[r][t] = h >= 0.f ? h : a1*h;
  }
  __syncthreads();
  #pragma unroll
  for (int r = 0; r < 16; r++) acc[r] = 0.f;
  const float4* w2p = reinterpret_cast<const float4*>(Wr2) + t*(NP/4);
  for (int k4 = 0; k4 < NP/4; k4++){
    float4 w = w2p[k4];
    #pragma unroll
    for (int r = 0; r < 16; r++){
      float4 hv = *reinterpret_cast<const float4*>(&H[r][k4*4]);
      acc[r] = fmaf(w.x, hv.x, acc[r]);
      acc[r] = fmaf(w.y, hv.y, acc[r]);
      acc[r] = fmaf(w.z, hv.z, acc[r]);
      acc[r] = fmaf(w.w, hv.w, acc[r]);
    }
  }
  const float b2 = br2[t];
  #pragma unroll
  for (int r = 0; r < 16; r++){
    int row = base + r;
    if (row < 2*NN + 1){
      float v = acc[r] + b2;
      float* op;
      if (row == 0){ op = zt; Zs[t] = v; }
      else if (row <= NN)  op = zf + (size_t)(row-1)*NP;
      else                 op = zr + (size_t)(row-NN-1)*NP;
      op[t] = v;
    }
  }

  // block 0: qk = (Wk^T @ (Wq@zt+bq))/sqrt(DD); s0 = (bk.(Wq@zt+bq))/sqrt(DD)
  if (blockIdx.x == 0){
    __syncthreads();               // Zs complete
    if (t < NDD){
      float a = 0.f;
      const float4* wq = reinterpret_cast<const float4*>(Wq) + t*(NP/4);
      for (int k4 = 0; k4 < NP/4; k4++){
        float4 w = wq[k4];
        float4 zv = *reinterpret_cast<const float4*>(&Zs[k4*4]);
        a = fmaf(w.x, zv.x, fmaf(w.y, zv.y, fmaf(w.z, zv.z, fmaf(w.w, zv.w, a))));
      }
      float qv = a + bq[t];
      Q[t] = qv;
      red[t] = bk[t] * qv;
    }
    __syncthreads();
    const float rs = 0.08838834764831845f;  // 1/sqrt(128)
    if (t < NDD){
      float a2 = 0.f;
      for (int j = 0; j < NDD; j++) a2 = fmaf(Wk[j*NDD + t], Q[j], a2);
      qk[t] = a2 * rs;
    }
    for (int o = 64; o; o >>= 1){
      if (t < o) red[t] += red[t+o];
      __syncthreads();
    }
    if (t == 0) s0[0] = red[0] * rs;
  }
}

// ---------------------------------------------------------------------------
// Segment id: fast path (sorted int neighbors with neigh[s]==s => pos=s),
// fallback to binary search.
// ---------------------------------------------------------------------------
__device__ __forceinline__ int seg_of(const int* NB, int s){
  if ((unsigned)s < NN && NB[s] == s) return s;
  int lo = 0, hi = NN;
  while (lo < hi){ int mid = (lo+hi)>>1; if (NB[mid] < s) lo = mid+1; else hi = mid; }
  return lo < NN ? lo : NN-1;
}

// ---------------------------------------------------------------------------
// K2: scatter edges into segment-sorted order. Absorbs the scan: every block
// redundantly computes the exclusive prefix sum of count in LDS; a zero-based
// global cursor gives each block a contiguous slot range per segment.
// Block 0 of each layer publishes the offsets array for seg_kernel.
// ---------------------------------------------------------------------------
__global__ __launch_bounds__(1024) void scatter_kernel(
    const int* __restrict__ neighF, const int* __restrict__ srcF,
    const int* __restrict__ dstF, const float* __restrict__ yF,
    const int* __restrict__ neighR, const int* __restrict__ srcR,
    const int* __restrict__ dstR, const float* __restrict__ yR,
    const int* __restrict__ count, int* __restrict__ cursor0,
    int* __restrict__ offsets, int2* __restrict__ edges)
{
  __shared__ int NB[NN];
  __shared__ int lcur[NN];
  __shared__ int sscan[NN];
  __shared__ int obase[NN];
  __shared__ int lbase[NN];
  int bi = blockIdx.x;
  int role = bi >= SB ? 1 : 0;
  int blk = bi - role*SB;
  const int* neigh = role ? neighR : neighF;
  const int* src   = role ? srcR   : srcF;
  const int* dst   = role ? dstR   : dstF;
  const float* yb  = role ? yR     : yF;
  int* cur0 = cursor0 + role*NN;
  int2* ed  = edges   + (size_t)role*NE;
  int t = threadIdx.x;
  NB[t] = neigh[t];
  lcur[t] = 0;
  int c0 = count[role*NN + t];
  sscan[t] = c0;
  __syncthreads();
  // exclusive scan of counts
  for (int o = 1; o < NN; o <<= 1){
    int v = (t >= o) ? sscan[t-o] : 0;
    __syncthreads();
    sscan[t] += v;
    __syncthreads();
  }
  obase[t] = sscan[t] - c0;
  if (blk == 0) offsets[role*NN + t] = sscan[t] - c0;
  __syncthreads();

  int segr[4], locr[4]; int2 edr[4];
  #pragma unroll
  for (int i = 0; i < 4; i++){
    int e = blk*4096 + i*1024 + t;
    segr[i] = -1;
    if (e < NE){
      int s = src[e];
      int pos = seg_of(NB, s);
      if (NB[pos] == s){
        segr[i] = pos;
        edr[i]  = make_int2(dst[e], __float_as_int(yb[e]));
        locr[i] = atomicAdd(&lcur[pos], 1);
      }
    }
  }
  __syncthreads();
  int c = lcur[t];
  if (c > 0) lbase[t] = obase[t] + atomicAdd(&cur0[t], c);
  __syncthreads();
  #pragma unroll
  for (int i = 0; i < 4; i++){
    if (segr[i] >= 0){
      ed[(size_t)(lbase[segr[i]] + locr[i])] = edr[i];
    }
  }
}

// ---------------------------------------------------------------------------
// K3: per-(layer,segment) softmax-weighted accumulation.
// 4 waves/block; each 32-lane half-wave handles one edge with float4 lanes.
// No max-subtraction: logits are O(1e-2), exp safe; num/den invariant.
// ---------------------------------------------------------------------------
__global__ __launch_bounds__(256) void seg_kernel(
    const float* __restrict__ drug,
    const int2* __restrict__ edges,
    const int* __restrict__ offsets, const int* __restrict__ count,
    const float* __restrict__ qk, const float* __restrict__ s0p,
    float* __restrict__ g, float* __restrict__ den, float* __restrict__ cfac)
{
  int b = blockIdx.x;                 // l*1024 + n
  int tid = threadIdx.x;
  int w = tid >> 6, lane = tid & 63, l32 = lane & 31, half = lane >> 5;
  int off = offsets[b], cnt = count[b];
  int l = b >> 10;
  const int2* eb = edges + (size_t)l*NE;
  float4 q = reinterpret_cast<const float4*>(qk)[l32];
  float s0 = s0p[0];
  int chunk = (cnt + 3) >> 2;
  int start = w*chunk;
  int end = min(start + chunk, cnt);
  float dn = 0.f, cc = 0.f;
  float4 ga = make_float4(0.f,0.f,0.f,0.f);
  for (int i = start; i < end; i += 8){
    int dstp[4]; float yp[4]; bool vp[4];
    #pragma unroll
    for (int p2 = 0; p2 < 4; p2++){
      int idx = i + 2*p2 + half;
      bool v = idx < end;
      int2 e = eb[off + (v ? idx : start)];
      dstp[p2] = e.x; yp[p2] = __int_as_float(e.y); vp[p2] = v;
    }
    float4 dv[4];
    #pragma unroll
    for (int p2 = 0; p2 < 4; p2++){
      dv[p2] = reinterpret_cast<const float4*>(drug + (size_t)dstp[p2]*NDD)[l32];
    }
    #pragma unroll
    for (int p2 = 0; p2 < 4; p2++){
      float4 d = dv[p2];
      float s = fmaf(d.x, q.x, fmaf(d.y, q.y, fmaf(d.z, q.z, d.w*q.w)));
      s += __shfl_xor(s, 16, 64);
      s += __shfl_xor(s,  8, 64);
      s += __shfl_xor(s,  4, 64);
      s += __shfl_xor(s,  2, 64);
      s += __shfl_xor(s,  1, 64);
      float ex = vp[p2] ? __expf(s + s0) : 0.f;
      float wv = ex * (yp[p2] - 6.0f);
      dn += ex; cc += wv;
      ga.x = fmaf(wv, d.x, ga.x);
      ga.y = fmaf(wv, d.y, ga.y);
      ga.z = fmaf(wv, d.z, ga.z);
      ga.w = fmaf(wv, d.w, ga.w);
    }
  }
  __shared__ float4 sG[8][32];
  __shared__ float sD[8], sC[8];
  int slot = w*2 + half;
  sG[slot][l32] = ga;
  if (l32 == 0){ sD[slot] = dn; sC[slot] = cc; }
  __syncthreads();
  if (tid < NDD){
    int a = tid >> 2, c = tid & 3;
    float v = 0.f;
    #pragma unroll
    for (int k = 0; k < 8; k++)
      v += reinterpret_cast<const float*>(&sG[k][a])[c];
    g[(size_t)b*NDD + tid] = v;
    if (tid == 0){
      float ds = 0.f, cs = 0.f;
      #pragma unroll
      for (int k = 0; k < 8; k++){ ds += sD[k]; cs += sC[k]; }
      den[b] = ds; cfac[b] = cs;
    }
  }
}

// ---------------------------------------------------------------------------
// K4: fused attn (blocks 0..255) + msgs (blocks 256..511), 256 threads each.
// ---------------------------------------------------------------------------
__global__ __launch_bounds__(256) void attn_msgs_kernel(
    const float* __restrict__ zt, const float* __restrict__ zf, const float* __restrict__ zr,
    const float* __restrict__ lemb,
    const float* __restrict__ Wa1, const float* __restrict__ ba1,
    const float* __restrict__ Wa2, const float* __restrict__ ba2,
    const float* __restrict__ Wa3, const float* __restrict__ ba3,
    const float* __restrict__ g, const float* __restrict__ den, const float* __restrict__ cfac,
    const float* __restrict__ Wv, const float* __restrict__ bv,
    float* __restrict__ attn, float* __restrict__ msgsf, float* __restrict__ outm)
{
  int t = threadIdx.x;
  int tt = t & 127, grp = t >> 7;
  if (blockIdx.x < 256){
    // ---------------- attn ----------------
    __shared__ float X[8][528];
    __shared__ float H1[8][NDD];
    int base = blockIdx.x*8;
    for (int r = 0; r < 8; r++){
      int i = base + r;
      int layer = i >> 10, nn = i & (NN-1);
      const float* zn = (layer == 0) ? (zf + (size_t)nn*NP) : (zr + (size_t)nn*NP);
      for (int idx = t; idx < 528; idx += 256){
        float v;
        if (idx < NP)        v = zt[idx];
        else if (idx < 2*NP) v = zn[idx - NP];
        else                 v = lemb[layer*16 + (idx - 2*NP)];
        X[r][idx] = v;
      }
    }
    __syncthreads();
    float acc[4];
    #pragma unroll
    for (int r = 0; r < 4; r++) acc[r] = 0.f;
    const float4* w1 = reinterpret_cast<const float4*>(Wa1) + tt*(528/4);
    for (int k4 = 0; k4 < 132; k4++){
      float4 w = w1[k4];
      #pragma unroll
      for (int r = 0; r < 4; r++){
        float4 xv = *reinterpret_cast<const float4*>(&X[grp*4 + r][k4*4]);
        acc[r] = fmaf(w.x, xv.x, acc[r]);
        acc[r] = fmaf(w.y, xv.y, acc[r]);
        acc[r] = fmaf(w.z, xv.z, acc[r]);
        acc[r] = fmaf(w.w, xv.w, acc[r]);
      }
    }
    float b1 = ba1[tt];
    #pragma unroll
    for (int r = 0; r < 4; r++){
      float h = acc[r] + b1;
      H1[grp*4 + r][tt] = h >= 0.f ? h : 0.2f*h;
    }
    __syncthreads();
    if (tt < 64){
      float acc2[4];
      #pragma unroll
      for (int r = 0; r < 4; r++) acc2[r] = 0.f;
      const float4* w2 = reinterpret_cast<const float4*>(Wa2) + tt*(NDD/4);
      for (int k4 = 0; k4 < NDD/4; k4++){
        float4 w = w2[k4];
        #pragma unroll
        for (int r = 0; r < 4; r++){
          float4 hv = *reinterpret_cast<const float4*>(&H1[grp*4 + r][k4*4]);
          acc2[r] = fmaf(w.x, hv.x, acc2[r]);
          acc2[r] = fmaf(w.y, hv.y, acc2[r]);
          acc2[r] = fmaf(w.z, hv.z, acc2[r]);
          acc2[r] = fmaf(w.w, hv.w, acc2[r]);
        }
      }
      float b2 = ba2[tt];
      float w3 = Wa3[tt];
      float b3 = ba3[0];
      #pragma unroll
      for (int r = 0; r < 4; r++){
        float h = acc2[r] + b2;
        h = h >= 0.f ? h : 0.2f*h;
        float p = w3 * h;
        #pragma unroll
        for (int o = 32; o; o >>= 1) p += __shfl_xor(p, o, 64);
        if (tt == 0) attn[base + grp*4 + r] = p + b3;
      }
    }
  } else {
    // ---------------- msgs ----------------
    __shared__ float G[8][NDD];
    int base = (blockIdx.x - 256)*8;
    #pragma unroll
    for (int r = 0; r < 4; r++) G[grp*4 + r][tt] = g[(size_t)(base + grp*4 + r)*NDD + tt];
    __syncthreads();
    float acc[4];
    #pragma unroll
    for (int r = 0; r < 4; r++) acc[r] = 0.f;
    const float4* wv4 = reinterpret_cast<const float4*>(Wv) + tt*(NDD/4);
    for (int k4 = 0; k4 < NDD/4; k4++){
      float4 w = wv4[k4];
      #pragma unroll
      for (int r = 0; r < 4; r++){
        float4 gv = *reinterpret_cast<const float4*>(&G[grp*4 + r][k4*4]);
        acc[r] = fmaf(w.x, gv.x, acc[r]);
        acc[r] = fmaf(w.y, gv.y, acc[r]);
        acc[r] = fmaf(w.z, gv.z, acc[r]);
        acc[r] = fmaf(w.w, gv.w, acc[r]);
      }
    }
    float bvj = bv[tt];
    #pragma unroll
    for (int r = 0; r < 4; r++){
      int row = base + grp*4 + r;
      float dn = den[row];
      float v = 0.f;
      if (dn > 0.f) v = (acc[r] + bvj*cfac[row]) / fmaxf(dn, 1e-30f);
      msgsf[(size_t)row*NDD + tt] = v;
      outm [(size_t)row*NDD + tt] = v;
    }
  }
}

// ---------------------------------------------------------------------------
// K5: fused vprior + final. One 1024-thread block.
// ---------------------------------------------------------------------------
__global__ __launch_bounds__(1024) void vprior_final_kernel(
    const float* __restrict__ attn, const float* __restrict__ msgsf,
    const float* __restrict__ zt,
    const float* __restrict__ Wi1, const float* __restrict__ bi1, const float* __restrict__ ai,
    const float* __restrict__ Wi2, const float* __restrict__ bi2,
    const float* __restrict__ ln_g, const float* __restrict__ ln_b,
    float* __restrict__ zout)
{
  __shared__ float A[2*NN];
  __shared__ float red[1024];
  __shared__ float Pp[8][NDD];
  __shared__ float V[NDD];
  __shared__ float T1[NP];
  __shared__ float red2[NP];
  int t = threadIdx.x;
  A[t] = attn[t]; A[t+1024] = attn[t+1024];
  __syncthreads();
  float mx = fmaxf(A[t], A[t+1024]);
  red[t] = mx; __syncthreads();
  for (int o = 512; o; o >>= 1){ if (t < o) red[t] = fmaxf(red[t], red[t+o]); __syncthreads(); }
  float M = red[0]; __syncthreads();
  float sm = __expf(A[t] - M) + __expf(A[t+1024] - M);
  red[t] = sm; __syncthreads();
  for (int o = 512; o; o >>= 1){ if (t < o) red[t] += red[t+o]; __syncthreads(); }
  float inv = 1.f / red[0]; __syncthreads();
  A[t]      = __expf(A[t]      - M) * inv;
  A[t+1024] = __expf(A[t+1024] - M) * inv;
  __syncthreads();
  int j = t & 127, grp = t >> 7;          // 8 groups x 128 dims
  float acc = 0.f;
  int i0 = grp * 256;
  for (int i = i0; i < i0 + 256; i++) acc = fmaf(A[i], msgsf[(size_t)i*NDD + j], acc);
  Pp[grp][j] = acc;
  __syncthreads();
  if (t < NDD){
    float v = 0.f;
    #pragma unroll
    for (int gg = 0; gg < 8; gg++) v += Pp[gg][t];
    V[t] = v;
  }
  __syncthreads();
  float x = 0.f;
  if (t < NP){
    float a1 = 0.f;
    const float4* w1 = reinterpret_cast<const float4*>(Wi1) + t*(NDD/4);
    for (int k4 = 0; k4 < NDD/4; k4++){
      float4 w = w1[k4];
      float4 vv = *reinterpret_cast<const float4*>(&V[k4*4]);
      a1 = fmaf(w.x, vv.x, fmaf(w.y, vv.y, fmaf(w.z, vv.z, fmaf(w.w, vv.w, a1))));
    }
    float h = a1 + bi1[t];
    float a = ai[0];
    T1[t] = h >= 0.f ? h : a*h;
  }
  __syncthreads();
  if (t < NP){
    float a2 = 0.f;
    const float4* w2 = reinterpret_cast<const float4*>(Wi2) + t*(NP/4);
    for (int k4 = 0; k4 < NP/4; k4++){
      float4 w = w2[k4];
      float4 hv = *reinterpret_cast<const float4*>(&T1[k4*4]);
      a2 = fmaf(w.x, hv.x, fmaf(w.y, hv.y, fmaf(w.z, hv.z, fmaf(w.w, hv.w, a2))));
    }
    x = zt[t] + a2 + bi2[t];
    red2[t] = x;
  }
  __syncthreads();
  for (int o = 128; o; o >>= 1){ if (t < o) red2[t] += red2[t+o]; __syncthreads(); }
  float mu = red2[0] * (1.f/256.f); __syncthreads();
  float d = x - mu;
  if (t < NP) red2[t] = d*d;
  __syncthreads();
  for (int o = 128; o; o >>= 1){ if (t < o) red2[t] += red2[t+o]; __syncthreads(); }
  if (t < NP){
    float var = red2[0] * (1.f/256.f);
    float zz = d * rsqrtf(var + 1e-5f) * ln_g[t] + ln_b[t];
    zout[t] = zz;
  }
}

// ---------------------------------------------------------------------------
extern "C" void kernel_launch(void* const* d_in, const int* in_sizes, int n_in,
                              void* d_out, int out_size, void* d_ws, size_t ws_size,
                              hipStream_t stream)
{
  const float* tgt    = (const float*)d_in[0];
  const float* formf  = (const float*)d_in[1];
  const float* rolef  = (const float*)d_in[2];
  const int* fneigh   = (const int*)d_in[3];
  const int* fsrc     = (const int*)d_in[4];
  const int* fdst     = (const int*)d_in[5];
  const float* fy     = (const float*)d_in[6];
  const int* rneigh   = (const int*)d_in[7];
  const int* rsrc     = (const int*)d_in[8];
  const int* rdst     = (const int*)d_in[9];
  const float* ry     = (const float*)d_in[10];
  const float* drug   = (const float*)d_in[11];
  const float* Wr1 = (const float*)d_in[12];
  const float* br1 = (const float*)d_in[13];
  const float* ar1 = (const float*)d_in[14];
  const float* Wr2 = (const float*)d_in[15];
  const float* br2 = (const float*)d_in[16];
  const float* Wq  = (const float*)d_in[17];
  const float* bq  = (const float*)d_in[18];
  const float* Wk  = (const float*)d_in[19];
  const float* bk  = (const float*)d_in[20];
  const float* Wv  = (const float*)d_in[21];
  const float* bv  = (const float*)d_in[22];
  const float* lemb= (const float*)d_in[23];
  const float* Wa1 = (const float*)d_in[24];
  const float* ba1 = (const float*)d_in[25];
  const float* Wa2 = (const float*)d_in[26];
  const float* ba2 = (const float*)d_in[27];
  const float* Wa3 = (const float*)d_in[28];
  const float* ba3 = (const float*)d_in[29];
  const float* Wi1 = (const float*)d_in[30];
  const float* bi1 = (const float*)d_in[31];
  const float* ai  = (const float*)d_in[32];
  const float* Wi2 = (const float*)d_in[33];
  const float* bi2 = (const float*)d_in[34];
  const float* lng = (const float*)d_in[35];
  const float* lnb = (const float*)d_in[36];
  (void)in_sizes; (void)n_in; (void)out_size; (void)ws_size;

  float* ws = (float*)d_ws;
  // ws layout (float offsets)
  float* zt_     = ws + 0;
  float* zf_     = ws + 256;
  float* zr_     = ws + 262400;
  float* qk_     = ws + 524544;
  float* s0_     = ws + 524672;
  float* attn_   = ws + 524800;
  float* den_    = ws + 527104;
  float* cfac_   = ws + 529152;
  float* g_      = ws + 531200;
  float* msgsf_  = ws + 793344;
  int*   count_  = (int*)(ws + 1055488);
  int*   offs_   = (int*)(ws + 1057536);
  int*   cursor_ = (int*)(ws + 1059584);
  int2*  edges_  = (int2*)(ws + 1061632);   // 2*NE int2 = 1M ints

  // zero count_ / offs_ / cursor_ (contiguous 3*2048 ints; offs_ rewritten later)
  hipMemsetAsync(count_, 0, 3*2*NN*sizeof(int), stream);

  refine_qk_hist_kernel<<<RB + 2*SB, 256, 0, stream>>>(
      tgt, formf, rolef, Wr1, br1, ar1, Wr2, br2, Wq, bq, Wk, bk,
      fneigh, fsrc, rneigh, rsrc,
      zt_, zf_, zr_, qk_, s0_, count_);

  scatter_kernel<<<2*SB, 1024, 0, stream>>>(fneigh, fsrc, fdst, fy,
                                            rneigh, rsrc, rdst, ry,
                                            count_, cursor_, offs_, edges_);

  seg_kernel<<<2*NN, 256, 0, stream>>>(drug, edges_, offs_, count_, qk_, s0_,
                                       g_, den_, cfac_);

  attn_msgs_kernel<<<512, 256, 0, stream>>>(zt_, zf_, zr_, lemb,
                                            Wa1, ba1, Wa2, ba2, Wa3, ba3,
                                            g_, den_, cfac_, Wv, bv,
                                            attn_, msgsf_, (float*)d_out + NP);
  vprior_final_kernel<<<1, 1024, 0, stream>>>(attn_, msgsf_, zt_,
                                              Wi1, bi1, ai, Wi2, bi2,
                                              lng, lnb, (float*)d_out);
}

// Round 7
// 368.386 us; speedup vs baseline: 1.0652x; 1.0609x over previous
//
#include <hip/hip_runtime.h>

#define NP 256      // P
#define NDD 128     // DD
#define NN 1024     // N
#define NE 250000   // E
#define SB 62       // ceil(NE/4096) blocks per layer for hist/scatter
#define RB2 257     // ceil(2049/8) refine blocks

// ---------------------------------------------------------------------------
// K0: prep — transpose weights into ws so inner loops read coalesced.
//  blocks 0..15  : Wr1 [256][256] -> Wr1T
//  blocks 16..31 : Wr2 [256][256] -> Wr2T
//  blocks 32..39 : Wa1 cols 256..511 of [128][528] -> Wa1mT [256][128]
//  blocks 40..41 : Wa2 [64][128] -> Wa2T [128][64]
//  blocks 42..45 : Wv  [128][128] -> WvT
// ---------------------------------------------------------------------------
__global__ __launch_bounds__(256) void prep_kernel(
    const float* __restrict__ Wr1, const float* __restrict__ Wr2,
    const float* __restrict__ Wa1, const float* __restrict__ Wa2,
    const float* __restrict__ Wv,
    float* __restrict__ Wr1T, float* __restrict__ Wr2T,
    float* __restrict__ Wa1mT, float* __restrict__ Wa2T, float* __restrict__ WvT)
{
  __shared__ float T[64][65];
  int b = blockIdx.x, t = threadIdx.x;
  const float* src; float* dst;
  int sC, sr0, sc0, dC, dr0, dc0;
  if (b < 16){        int ti=b;    src=Wr1; sC=256; sr0=(ti/4)*64; sc0=(ti%4)*64;
                      dst=Wr1T; dC=256; dr0=sc0; dc0=sr0; }
  else if (b < 32){   int ti=b-16; src=Wr2; sC=256; sr0=(ti/4)*64; sc0=(ti%4)*64;
                      dst=Wr2T; dC=256; dr0=sc0; dc0=sr0; }
  else if (b < 40){   int ti=b-32; src=Wa1; sC=528; sr0=(ti/4)*64; sc0=256+(ti%4)*64;
                      dst=Wa1mT; dC=128; dr0=(ti%4)*64; dc0=sr0; }
  else if (b < 42){   int ti=b-40; src=Wa2; sC=128; sr0=0; sc0=ti*64;
                      dst=Wa2T; dC=64; dr0=sc0; dc0=0; }
  else {              int ti=b-42; src=Wv;  sC=128; sr0=(ti/2)*64; sc0=(ti%2)*64;
                      dst=WvT; dC=128; dr0=sc0; dc0=sr0; }
  #pragma unroll
  for (int j = 0; j < 16; j++){
    int idx = t + j*256;
    int r = idx >> 6, c = idx & 63;
    T[c][r] = src[(size_t)(sr0 + r)*sC + sc0 + c];
  }
  __syncthreads();
  #pragma unroll
  for (int j = 0; j < 16; j++){
    int idx = t + j*256;
    int r = idx >> 6, c = idx & 63;
    dst[(size_t)(dr0 + r)*dC + dc0 + c] = T[r][c];
  }
}

// ---------------------------------------------------------------------------
// K1: fused refine (blocks 0..RB2-1, 8 rows each) + hist (blocks RB2..).
// refine inner loop: thread t = output feature; coalesced W^T reads,
// X broadcast from LDS as float4 per 4-k group.
// Block 0 additionally computes qk, s0, and c_l = Wa1[:, :256]@zt
//   + Wa1[:, 512:528]@le_l + ba1 (layer-uniform part of attn stage 1).
// ---------------------------------------------------------------------------
__global__ __launch_bounds__(256) void refine_qk_hist_kernel(
    const float* __restrict__ tgt, const float* __restrict__ formf, const float* __restrict__ rolef,
    const float* __restrict__ Wr1T, const float* __restrict__ br1, const float* __restrict__ ar1,
    const float* __restrict__ Wr2T, const float* __restrict__ br2,
    const float* __restrict__ Wq, const float* __restrict__ bq,
    const float* __restrict__ Wk, const float* __restrict__ bk,
    const float* __restrict__ Wa1, const float* __restrict__ ba1, const float* __restrict__ lemb,
    const int* __restrict__ neighF, const int* __restrict__ srcF,
    const int* __restrict__ neighR, const int* __restrict__ srcR,
    float* __restrict__ zt, float* __restrict__ zf, float* __restrict__ zr,
    float* __restrict__ qk, float* __restrict__ s0, float* __restrict__ cl,
    int* __restrict__ count)
{
  __shared__ float X[8][NP];      // 8 KB (hist overlays NB/lh here)
  __shared__ float H[8][NP];      // 8 KB
  __shared__ float Zs[NP];
  __shared__ float Q[NDD];
  __shared__ float red[NDD];
  const int t = threadIdx.x;

  if (blockIdx.x >= RB2){
    // ------------------------- hist path -------------------------
    int bi = blockIdx.x - RB2;
    int role = bi >= SB ? 1 : 0;
    int blk = bi - role*SB;
    const int* neigh = role ? neighR : neighF;
    const int* src   = role ? srcR   : srcF;
    int* cnt = count + role*NN;
    int* NB = (int*)&X[0][0];
    int* lh = NB + NN;
    #pragma unroll
    for (int i = 0; i < NN/256; i++){
      NB[t + i*256] = neigh[t + i*256];
      lh[t + i*256] = 0;
    }
    __syncthreads();
    #pragma unroll
    for (int i = 0; i < 16; i++){
      int e = blk*4096 + i*256 + t;
      if (e < NE){
        int s = src[e];
        int pos;
        if ((unsigned)s < NN && NB[s] == s) pos = s;
        else {
          int lo = 0, hi = NN;
          while (lo < hi){ int mid = (lo+hi)>>1; if (NB[mid] < s) lo = mid+1; else hi = mid; }
          pos = lo < NN ? lo : NN-1;
        }
        if (NB[pos] == s) atomicAdd(&lh[pos], 1);
      }
    }
    __syncthreads();
    #pragma unroll
    for (int i = 0; i < NN/256; i++){
      int c = lh[t + i*256];
      if (c > 0) atomicAdd(&cnt[t + i*256], c);
    }
    return;
  }

  // ------------------------- refine path -------------------------
  const int base = blockIdx.x * 8;
  #pragma unroll
  for (int r = 0; r < 8; r++){
    int row = base + r;
    if (row < 2*NN + 1){
      const float* xp;
      if (row == 0)        xp = tgt;
      else if (row <= NN)  xp = formf + (size_t)(row-1)*NP;
      else                 xp = rolef + (size_t)(row-NN-1)*NP;
      X[r][t] = xp[t];
    } else {
      X[r][t] = 0.f;
    }
  }
  __syncthreads();
  const float a1 = ar1[0];
  float acc[8];
  #pragma unroll
  for (int r = 0; r < 8; r++) acc[r] = 0.f;
  for (int k = 0; k < NP; k += 4){
    float w0 = Wr1T[(k+0)*NP + t];
    float w1 = Wr1T[(k+1)*NP + t];
    float w2 = Wr1T[(k+2)*NP + t];
    float w3 = Wr1T[(k+3)*NP + t];
    #pragma unroll
    for (int r = 0; r < 8; r++){
      float4 x = *reinterpret_cast<const float4*>(&X[r][k]);
      acc[r] = fmaf(w0, x.x, acc[r]);
      acc[r] = fmaf(w1, x.y, acc[r]);
      acc[r] = fmaf(w2, x.z, acc[r]);
      acc[r] = fmaf(w3, x.w, acc[r]);
    }
  }
  const float b1 = br1[t];
  #pragma unroll
  for (int r = 0; r < 8; r++){
    float h = acc[r] + b1;
    H[r][t] = h >= 0.f ? h : a1*h;
  }
  __syncthreads();
  #pragma unroll
  for (int r = 0; r < 8; r++) acc[r] = 0.f;
  for (int k = 0; k < NP; k += 4){
    float w0 = Wr2T[(k+0)*NP + t];
    float w1 = Wr2T[(k+1)*NP + t];
    float w2 = Wr2T[(k+2)*NP + t];
    float w3 = Wr2T[(k+3)*NP + t];
    #pragma unroll
    for (int r = 0; r < 8; r++){
      float4 h4 = *reinterpret_cast<const float4*>(&H[r][k]);
      acc[r] = fmaf(w0, h4.x, acc[r]);
      acc[r] = fmaf(w1, h4.y, acc[r]);
      acc[r] = fmaf(w2, h4.z, acc[r]);
      acc[r] = fmaf(w3, h4.w, acc[r]);
    }
  }
  const float b2 = br2[t];
  #pragma unroll
  for (int r = 0; r < 8; r++){
    int row = base + r;
    if (row < 2*NN + 1){
      float v = acc[r] + b2;
      float* op;
      if (row == 0){ op = zt; Zs[t] = v; }
      else if (row <= NN)  op = zf + (size_t)(row-1)*NP;
      else                 op = zr + (size_t)(row-NN-1)*NP;
      op[t] = v;
    }
  }

  if (blockIdx.x == 0){
    __syncthreads();               // Zs complete
    // qk / s0
    if (t < NDD){
      float a = 0.f;
      const float4* wq = reinterpret_cast<const float4*>(Wq) + t*(NP/4);
      for (int k4 = 0; k4 < NP/4; k4++){
        float4 w = wq[k4];
        float4 zv = *reinterpret_cast<const float4*>(&Zs[k4*4]);
        a = fmaf(w.x, zv.x, fmaf(w.y, zv.y, fmaf(w.z, zv.z, fmaf(w.w, zv.w, a))));
      }
      float qv = a + bq[t];
      Q[t] = qv;
      red[t] = bk[t] * qv;
    }
    __syncthreads();
    const float rs = 0.08838834764831845f;  // 1/sqrt(128)
    if (t < NDD){
      float a2 = 0.f;
      for (int j = 0; j < NDD; j++) a2 = fmaf(Wk[j*NDD + t], Q[j], a2);
      qk[t] = a2 * rs;
    }
    for (int o = 64; o; o >>= 1){
      if (t < o) red[t] += red[t+o];
      __syncthreads();
    }
    if (t == 0) s0[0] = red[0] * rs;
    // c_l (l = t>>7, tt = t&127): Wa1[tt, :256]@zt + Wa1[tt, 512:528]@le_l + ba1
    {
      int l = t >> 7, tt = t & 127;
      const float4* wrow = reinterpret_cast<const float4*>(Wa1 + (size_t)tt*528);
      float a = 0.f;
      for (int k4 = 0; k4 < 64; k4++){
        float4 w = wrow[k4];
        float4 zv = *reinterpret_cast<const float4*>(&Zs[k4*4]);
        a = fmaf(w.x, zv.x, fmaf(w.y, zv.y, fmaf(w.z, zv.z, fmaf(w.w, zv.w, a))));
      }
      const float* wle = Wa1 + (size_t)tt*528 + 512;
      const float* le = lemb + l*16;
      #pragma unroll
      for (int j = 0; j < 16; j++) a = fmaf(wle[j], le[j], a);
      cl[l*NDD + tt] = a + ba1[tt];
    }
  }
}

// ---------------------------------------------------------------------------
__device__ __forceinline__ int seg_of(const int* NB, int s){
  if ((unsigned)s < NN && NB[s] == s) return s;
  int lo = 0, hi = NN;
  while (lo < hi){ int mid = (lo+hi)>>1; if (NB[mid] < s) lo = mid+1; else hi = mid; }
  return lo < NN ? lo : NN-1;
}

// ---------------------------------------------------------------------------
// K2: scatter (absorbs scan, two-level LDS aggregation). Unchanged.
// ---------------------------------------------------------------------------
__global__ __launch_bounds__(1024) void scatter_kernel(
    const int* __restrict__ neighF, const int* __restrict__ srcF,
    const int* __restrict__ dstF, const float* __restrict__ yF,
    const int* __restrict__ neighR, const int* __restrict__ srcR,
    const int* __restrict__ dstR, const float* __restrict__ yR,
    const int* __restrict__ count, int* __restrict__ cursor0,
    int* __restrict__ offsets, int2* __restrict__ edges)
{
  __shared__ int NB[NN];
  __shared__ int lcur[NN];
  __shared__ int sscan[NN];
  __shared__ int obase[NN];
  __shared__ int lbase[NN];
  int bi = blockIdx.x;
  int role = bi >= SB ? 1 : 0;
  int blk = bi - role*SB;
  const int* neigh = role ? neighR : neighF;
  const int* src   = role ? srcR   : srcF;
  const int* dst   = role ? dstR   : dstF;
  const float* yb  = role ? yR     : yF;
  int* cur0 = cursor0 + role*NN;
  int2* ed  = edges   + (size_t)role*NE;
  int t = threadIdx.x;
  NB[t] = neigh[t];
  lcur[t] = 0;
  int c0 = count[role*NN + t];
  sscan[t] = c0;
  __syncthreads();
  for (int o = 1; o < NN; o <<= 1){
    int v = (t >= o) ? sscan[t-o] : 0;
    __syncthreads();
    sscan[t] += v;
    __syncthreads();
  }
  obase[t] = sscan[t] - c0;
  if (blk == 0) offsets[role*NN + t] = sscan[t] - c0;
  __syncthreads();

  int segr[4], locr[4]; int2 edr[4];
  #pragma unroll
  for (int i = 0; i < 4; i++){
    int e = blk*4096 + i*1024 + t;
    segr[i] = -1;
    if (e < NE){
      int s = src[e];
      int pos = seg_of(NB, s);
      if (NB[pos] == s){
        segr[i] = pos;
        edr[i]  = make_int2(dst[e], __float_as_int(yb[e]));
        locr[i] = atomicAdd(&lcur[pos], 1);
      }
    }
  }
  __syncthreads();
  int c = lcur[t];
  if (c > 0) lbase[t] = obase[t] + atomicAdd(&cur0[t], c);
  __syncthreads();
  #pragma unroll
  for (int i = 0; i < 4; i++){
    if (segr[i] >= 0){
      ed[(size_t)(lbase[segr[i]] + locr[i])] = edr[i];
    }
  }
}

// ---------------------------------------------------------------------------
// K3: per-(layer,segment) softmax-weighted accumulation. Unchanged.
// ---------------------------------------------------------------------------
__global__ __launch_bounds__(256) void seg_kernel(
    const float* __restrict__ drug,
    const int2* __restrict__ edges,
    const int* __restrict__ offsets, const int* __restrict__ count,
    const float* __restrict__ qk, const float* __restrict__ s0p,
    float* __restrict__ g, float* __restrict__ den, float* __restrict__ cfac)
{
  int b = blockIdx.x;                 // l*1024 + n
  int tid = threadIdx.x;
  int w = tid >> 6, lane = tid & 63, l32 = lane & 31, half = lane >> 5;
  int off = offsets[b], cnt = count[b];
  int l = b >> 10;
  const int2* eb = edges + (size_t)l*NE;
  float4 q = reinterpret_cast<const float4*>(qk)[l32];
  float s0 = s0p[0];
  int chunk = (cnt + 3) >> 2;
  int start = w*chunk;
  int end = min(start + chunk, cnt);
  float dn = 0.f, cc = 0.f;
  float4 ga = make_float4(0.f,0.f,0.f,0.f);
  for (int i = start; i < end; i += 8){
    int dstp[4]; float yp[4]; bool vp[4];
    #pragma unroll
    for (int p2 = 0; p2 < 4; p2++){
      int idx = i + 2*p2 + half;
      bool v = idx < end;
      int2 e = eb[off + (v ? idx : start)];
      dstp[p2] = e.x; yp[p2] = __int_as_float(e.y); vp[p2] = v;
    }
    float4 dv[4];
    #pragma unroll
    for (int p2 = 0; p2 < 4; p2++){
      dv[p2] = reinterpret_cast<const float4*>(drug + (size_t)dstp[p2]*NDD)[l32];
    }
    #pragma unroll
    for (int p2 = 0; p2 < 4; p2++){
      float4 d = dv[p2];
      float s = fmaf(d.x, q.x, fmaf(d.y, q.y, fmaf(d.z, q.z, d.w*q.w)));
      s += __shfl_xor(s, 16, 64);
      s += __shfl_xor(s,  8, 64);
      s += __shfl_xor(s,  4, 64);
      s += __shfl_xor(s,  2, 64);
      s += __shfl_xor(s,  1, 64);
      float ex = vp[p2] ? __expf(s + s0) : 0.f;
      float wv = ex * (yp[p2] - 6.0f);
      dn += ex; cc += wv;
      ga.x = fmaf(wv, d.x, ga.x);
      ga.y = fmaf(wv, d.y, ga.y);
      ga.z = fmaf(wv, d.z, ga.z);
      ga.w = fmaf(wv, d.w, ga.w);
    }
  }
  __shared__ float4 sG[8][32];
  __shared__ float sD[8], sC[8];
  int slot = w*2 + half;
  sG[slot][l32] = ga;
  if (l32 == 0){ sD[slot] = dn; sC[slot] = cc; }
  __syncthreads();
  if (tid < NDD){
    int a = tid >> 2, c = tid & 3;
    float v = 0.f;
    #pragma unroll
    for (int k = 0; k < 8; k++)
      v += reinterpret_cast<const float*>(&sG[k][a])[c];
    g[(size_t)b*NDD + tid] = v;
    if (tid == 0){
      float ds = 0.f, cs = 0.f;
      #pragma unroll
      for (int k = 0; k < 8; k++){ ds += sD[k]; cs += sC[k]; }
      den[b] = ds; cfac[b] = cs;
    }
  }
}

// ---------------------------------------------------------------------------
// K4: fused attn (blocks 0..255) + msgs (blocks 256..511), 256 threads.
// attn stage 1 uses precomputed c_l: h1 = lrelu(Wa1mid @ zn + c_l), K=256.
// All weight reads coalesced via transposed copies.
// ---------------------------------------------------------------------------
__global__ __launch_bounds__(256) void attn_msgs_kernel(
    const float* __restrict__ zf, const float* __restrict__ zr,
    const float* __restrict__ cl,
    const float* __restrict__ Wa1mT,
    const float* __restrict__ Wa2T, const float* __restrict__ ba2,
    const float* __restrict__ Wa3, const float* __restrict__ ba3,
    const float* __restrict__ g, const float* __restrict__ den, const float* __restrict__ cfac,
    const float* __restrict__ WvT, const float* __restrict__ bv,
    float* __restrict__ attn, float* __restrict__ msgsf, float* __restrict__ outm)
{
  int t = threadIdx.x;
  int tt = t & 127, grp = t >> 7;
  if (blockIdx.x < 256){
    // ---------------- attn ----------------
    __shared__ float Zn[8][NP];
    __shared__ float H1[8][NDD];
    int base = blockIdx.x*8;
    int layer = blockIdx.x >> 7;              // uniform per block
    const float* zsrc = layer ? zr : zf;
    #pragma unroll
    for (int r = 0; r < 8; r++){
      int nn = (base + r) & (NN-1);
      Zn[r][t] = zsrc[(size_t)nn*NP + t];
    }
    __syncthreads();
    float acc[4];
    #pragma unroll
    for (int r = 0; r < 4; r++) acc[r] = 0.f;
    for (int k = 0; k < NP; k += 4){
      float w0 = Wa1mT[(k+0)*NDD + tt];
      float w1 = Wa1mT[(k+1)*NDD + tt];
      float w2 = Wa1mT[(k+2)*NDD + tt];
      float w3 = Wa1mT[(k+3)*NDD + tt];
      #pragma unroll
      for (int r = 0; r < 4; r++){
        float4 x = *reinterpret_cast<const float4*>(&Zn[grp*4 + r][k]);
        acc[r] = fmaf(w0, x.x, acc[r]);
        acc[r] = fmaf(w1, x.y, acc[r]);
        acc[r] = fmaf(w2, x.z, acc[r]);
        acc[r] = fmaf(w3, x.w, acc[r]);
      }
    }
    float c1 = cl[layer*NDD + tt];
    #pragma unroll
    for (int r = 0; r < 4; r++){
      float h = acc[r] + c1;
      H1[grp*4 + r][tt] = h >= 0.f ? h : 0.2f*h;
    }
    __syncthreads();
    if (t < 64){
      float acc2[8];
      #pragma unroll
      for (int r = 0; r < 8; r++) acc2[r] = 0.f;
      for (int k = 0; k < NDD; k += 4){
        float w0 = Wa2T[(k+0)*64 + t];
        float w1 = Wa2T[(k+1)*64 + t];
        float w2 = Wa2T[(k+2)*64 + t];
        float w3 = Wa2T[(k+3)*64 + t];
        #pragma unroll
        for (int r = 0; r < 8; r++){
          float4 h4 = *reinterpret_cast<const float4*>(&H1[r][k]);
          acc2[r] = fmaf(w0, h4.x, acc2[r]);
          acc2[r] = fmaf(w1, h4.y, acc2[r]);
          acc2[r] = fmaf(w2, h4.z, acc2[r]);
          acc2[r] = fmaf(w3, h4.w, acc2[r]);
        }
      }
      float b2 = ba2[t];
      float w3v = Wa3[t];
      float b3 = ba3[0];
      #pragma unroll
      for (int r = 0; r < 8; r++){
        float h = acc2[r] + b2;
        h = h >= 0.f ? h : 0.2f*h;
        float p = w3v * h;
        #pragma unroll
        for (int o = 32; o; o >>= 1) p += __shfl_xor(p, o, 64);
        if (t == 0) attn[base + r] = p + b3;
      }
    }
  } else {
    // ---------------- msgs ----------------
    __shared__ float G[8][NDD];
    int base = (blockIdx.x - 256)*8;
    #pragma unroll
    for (int r = 0; r < 4; r++) G[grp*4 + r][tt] = g[(size_t)(base + grp*4 + r)*NDD + tt];
    __syncthreads();
    float acc[4];
    #pragma unroll
    for (int r = 0; r < 4; r++) acc[r] = 0.f;
    for (int k = 0; k < NDD; k += 4){
      float w0 = WvT[(k+0)*NDD + tt];
      float w1 = WvT[(k+1)*NDD + tt];
      float w2 = WvT[(k+2)*NDD + tt];
      float w3 = WvT[(k+3)*NDD + tt];
      #pragma unroll
      for (int r = 0; r < 4; r++){
        float4 gv = *reinterpret_cast<const float4*>(&G[grp*4 + r][k]);
        acc[r] = fmaf(w0, gv.x, acc[r]);
        acc[r] = fmaf(w1, gv.y, acc[r]);
        acc[r] = fmaf(w2, gv.z, acc[r]);
        acc[r] = fmaf(w3, gv.w, acc[r]);
      }
    }
    float bvj = bv[tt];
    #pragma unroll
    for (int r = 0; r < 4; r++){
      int row = base + grp*4 + r;
      float dn = den[row];
      float v = 0.f;
      if (dn > 0.f) v = (acc[r] + bvj*cfac[row]) / fmaxf(dn, 1e-30f);
      msgsf[(size_t)row*NDD + tt] = v;
      outm [(size_t)row*NDD + tt] = v;
    }
  }
}

// ---------------------------------------------------------------------------
// K5: fused vprior + final. One 1024-thread block. Unchanged.
// ---------------------------------------------------------------------------
__global__ __launch_bounds__(1024) void vprior_final_kernel(
    const float* __restrict__ attn, const float* __restrict__ msgsf,
    const float* __restrict__ zt,
    const float* __restrict__ Wi1, const float* __restrict__ bi1, const float* __restrict__ ai,
    const float* __restrict__ Wi2, const float* __restrict__ bi2,
    const float* __restrict__ ln_g, const float* __restrict__ ln_b,
    float* __restrict__ zout)
{
  __shared__ float A[2*NN];
  __shared__ float red[1024];
  __shared__ float Pp[8][NDD];
  __shared__ float V[NDD];
  __shared__ float T1[NP];
  __shared__ float red2[NP];
  int t = threadIdx.x;
  A[t] = attn[t]; A[t+1024] = attn[t+1024];
  __syncthreads();
  float mx = fmaxf(A[t], A[t+1024]);
  red[t] = mx; __syncthreads();
  for (int o = 512; o; o >>= 1){ if (t < o) red[t] = fmaxf(red[t], red[t+o]); __syncthreads(); }
  float M = red[0]; __syncthreads();
  float sm = __expf(A[t] - M) + __expf(A[t+1024] - M);
  red[t] = sm; __syncthreads();
  for (int o = 512; o; o >>= 1){ if (t < o) red[t] += red[t+o]; __syncthreads(); }
  float inv = 1.f / red[0]; __syncthreads();
  A[t]      = __expf(A[t]      - M) * inv;
  A[t+1024] = __expf(A[t+1024] - M) * inv;
  __syncthreads();
  int j = t & 127, grp = t >> 7;
  float acc = 0.f;
  int i0 = grp * 256;
  for (int i = i0; i < i0 + 256; i++) acc = fmaf(A[i], msgsf[(size_t)i*NDD + j], acc);
  Pp[grp][j] = acc;
  __syncthreads();
  if (t < NDD){
    float v = 0.f;
    #pragma unroll
    for (int gg = 0; gg < 8; gg++) v += Pp[gg][t];
    V[t] = v;
  }
  __syncthreads();
  float x = 0.f;
  if (t < NP){
    float a1 = 0.f;
    const float4* w1 = reinterpret_cast<const float4*>(Wi1) + t*(NDD/4);
    for (int k4 = 0; k4 < NDD/4; k4++){
      float4 w = w1[k4];
      float4 vv = *reinterpret_cast<const float4*>(&V[k4*4]);
      a1 = fmaf(w.x, vv.x, fmaf(w.y, vv.y, fmaf(w.z, vv.z, fmaf(w.w, vv.w, a1))));
    }
    float h = a1 + bi1[t];
    float a = ai[0];
    T1[t] = h >= 0.f ? h : a*h;
  }
  __syncthreads();
  if (t < NP){
    float a2 = 0.f;
    const float4* w2 = reinterpret_cast<const float4*>(Wi2) + t*(NP/4);
    for (int k4 = 0; k4 < NP/4; k4++){
      float4 w = w2[k4];
      float4 hv = *reinterpret_cast<const float4*>(&T1[k4*4]);
      a2 = fmaf(w.x, hv.x, fmaf(w.y, hv.y, fmaf(w.z, hv.z, fmaf(w.w, hv.w, a2))));
    }
    x = zt[t] + a2 + bi2[t];
    red2[t] = x;
  }
  __syncthreads();
  for (int o = 128; o; o >>= 1){ if (t < o) red2[t] += red2[t+o]; __syncthreads(); }
  float mu = red2[0] * (1.f/256.f); __syncthreads();
  float d = x - mu;
  if (t < NP) red2[t] = d*d;
  __syncthreads();
  for (int o = 128; o; o >>= 1){ if (t < o) red2[t] += red2[t+o]; __syncthreads(); }
  if (t < NP){
    float var = red2[0] * (1.f/256.f);
    float zz = d * rsqrtf(var + 1e-5f) * ln_g[t] + ln_b[t];
    zout[t] = zz;
  }
}

// ---------------------------------------------------------------------------
extern "C" void kernel_launch(void* const* d_in, const int* in_sizes, int n_in,
                              void* d_out, int out_size, void* d_ws, size_t ws_size,
                              hipStream_t stream)
{
  const float* tgt    = (const float*)d_in[0];
  const float* formf  = (const float*)d_in[1];
  const float* rolef  = (const float*)d_in[2];
  const int* fneigh   = (const int*)d_in[3];
  const int* fsrc     = (const int*)d_in[4];
  const int* fdst     = (const int*)d_in[5];
  const float* fy     = (const float*)d_in[6];
  const int* rneigh   = (const int*)d_in[7];
  const int* rsrc     = (const int*)d_in[8];
  const int* rdst     = (const int*)d_in[9];
  const float* ry     = (const float*)d_in[10];
  const float* drug   = (const float*)d_in[11];
  const float* Wr1 = (const float*)d_in[12];
  const float* br1 = (const float*)d_in[13];
  const float* ar1 = (const float*)d_in[14];
  const float* Wr2 = (const float*)d_in[15];
  const float* br2 = (const float*)d_in[16];
  const float* Wq  = (const float*)d_in[17];
  const float* bq  = (const float*)d_in[18];
  const float* Wk  = (const float*)d_in[19];
  const float* bk  = (const float*)d_in[20];
  const float* Wv  = (const float*)d_in[21];
  const float* bv  = (const float*)d_in[22];
  const float* lemb= (const float*)d_in[23];
  const float* Wa1 = (const float*)d_in[24];
  const float* ba1 = (const float*)d_in[25];
  const float* Wa2 = (const float*)d_in[26];
  const float* ba2 = (const float*)d_in[27];
  const float* Wa3 = (const float*)d_in[28];
  const float* ba3 = (const float*)d_in[29];
  const float* Wi1 = (const float*)d_in[30];
  const float* bi1 = (const float*)d_in[31];
  const float* ai  = (const float*)d_in[32];
  const float* Wi2 = (const float*)d_in[33];
  const float* bi2 = (const float*)d_in[34];
  const float* lng = (const float*)d_in[35];
  const float* lnb = (const float*)d_in[36];
  (void)in_sizes; (void)n_in; (void)out_size; (void)ws_size;

  float* ws = (float*)d_ws;
  // ws layout (float offsets)
  float* zt_     = ws + 0;
  float* zf_     = ws + 256;
  float* zr_     = ws + 262400;
  float* qk_     = ws + 524544;
  float* s0_     = ws + 524672;
  float* cl_     = ws + 524800;     // 2*128
  float* attn_   = ws + 525056;     // 2048
  float* den_    = ws + 527104;
  float* cfac_   = ws + 529152;
  float* g_      = ws + 531200;     // 262144
  float* msgsf_  = ws + 793344;     // 262144
  int*   count_  = (int*)(ws + 1055488);
  int*   offs_   = (int*)(ws + 1057536);
  int*   cursor_ = (int*)(ws + 1059584);
  int2*  edges_  = (int2*)(ws + 1061632);   // 2*NE int2 -> 2,000,000 floats
  float* Wr1T_   = ws + 3061632;    // 65536
  float* Wr2T_   = ws + 3127168;    // 65536
  float* Wa1mT_  = ws + 3192704;    // 32768
  float* Wa2T_   = ws + 3225472;    // 8192
  float* WvT_    = ws + 3233664;    // 16384

  hipMemsetAsync(count_, 0, 3*2*NN*sizeof(int), stream);

  prep_kernel<<<46, 256, 0, stream>>>(Wr1, Wr2, Wa1, Wa2, Wv,
                                      Wr1T_, Wr2T_, Wa1mT_, Wa2T_, WvT_);

  refine_qk_hist_kernel<<<RB2 + 2*SB, 256, 0, stream>>>(
      tgt, formf, rolef, Wr1T_, br1, ar1, Wr2T_, br2, Wq, bq, Wk, bk,
      Wa1, ba1, lemb,
      fneigh, fsrc, rneigh, rsrc,
      zt_, zf_, zr_, qk_, s0_, cl_, count_);

  scatter_kernel<<<2*SB, 1024, 0, stream>>>(fneigh, fsrc, fdst, fy,
                                            rneigh, rsrc, rdst, ry,
                                            count_, cursor_, offs_, edges_);

  seg_kernel<<<2*NN, 256, 0, stream>>>(drug, edges_, offs_, count_, qk_, s0_,
                                       g_, den_, cfac_);

  attn_msgs_kernel<<<512, 256, 0, stream>>>(zf_, zr_, cl_,
                                            Wa1mT_, Wa2T_, ba2, Wa3, ba3,
                                            g_, den_, cfac_, WvT_, bv,
                                            attn_, msgsf_, (float*)d_out + NP);
  vprior_final_kernel<<<1, 1024, 0, stream>>>(attn_, msgsf_, zt_,
                                              Wi1, bi1, ai, Wi2, bi2,
                                              lng, lnb, (float*)d_out);
}